// Round 7
// baseline (210.572 us; speedup 1.0000x reference)
//
#include <hip/hip_runtime.h>
#include <hip/hip_bf16.h>
#include <stdint.h>

#define Bn 8
#define Sn 4096
#define Hn 768
#define Dn 1024
#define Wn 2048

typedef __attribute__((ext_vector_type(8))) short short8;
typedef __attribute__((ext_vector_type(4))) short short4v;
typedef __attribute__((ext_vector_type(4))) float floatx4;

__device__ __forceinline__ void load_lds16(const void* g, void* l) {
  __builtin_amdgcn_global_load_lds(
      (const __attribute__((address_space(1))) void*)g,
      (__attribute__((address_space(3))) void*)l, 16, 0, 0);
}

// lane-parallel lower_bound over a sorted 4096-int array (wave-uniform result).
__device__ __forceinline__ int lb4096(const int* __restrict__ a, int x, int lane) {
  const int p = a[lane << 6];
  const unsigned long long m1 = __ballot(p < x);
  const int n1 = __popcll(m1);
  const int base = (n1 > 0 ? n1 - 1 : 0) << 6;
  const int q = a[base + lane];
  const unsigned long long m2 = __ballot(q < x);
  return base + __popcll(m2);
}

// -------- kernel 1: proj_w transpose  ∥  segment means + masks ------------------
// (unchanged from round 6 — measured good; transpose blocks first so they
//  overlap the word blocks' ramp instead of running as a serial tail)
__global__ __launch_bounds__(256) void k_front(const float* __restrict__ emb,
                                               const float* __restrict__ pw,
                                               const int* __restrict__ masks,
                                               const int* __restrict__ wid,
                                               __hip_bfloat16* __restrict__ wb,
                                               __hip_bfloat16* __restrict__ wa,
                                               float* __restrict__ out_masks) {
  const int bid = blockIdx.x;
  if (bid < 768) {
    __shared__ float tile[32][33];
    const int bt = bid;                   // 32 x 24 tile grid
    const int d0 = (bt % 32) * 32, h0 = (bt / 32) * 32;
    const int tx = threadIdx.x & 31, ty = threadIdx.x >> 5;  // 32 x 8
#pragma unroll
    for (int i = 0; i < 32; i += 8)
      tile[ty + i][tx] = pw[(size_t)(h0 + ty + i) * Dn + d0 + tx];
    __syncthreads();
#pragma unroll
    for (int i = 0; i < 32; i += 8)
      wb[(size_t)(d0 + ty + i) * Hn + h0 + tx] = (__hip_bfloat16)tile[tx][ty + i];
    return;
  }

  const int wbid = bid - 768;                // 0 .. 4095
  const int b = wbid >> 9;                   // 512 blocks per batch
  const int wave = threadIdx.x >> 6, lane = threadIdx.x & 63;
  const int w = (wbid & 511) * 4 + wave;

  const int* wbi = wid + (size_t)b * Sn;
  const int start = lb4096(wbi, w, lane);
  const int end = lb4096(wbi, w + 1, lane);
  const int count = end - start;

  const int* mb = masks + (size_t)b * Sn;
  bool allone = true;
  for (int s0 = start; s0 < end; s0 += 64) {
    const int idx = s0 + lane;
    allone = allone && ((idx < end) ? (mb[idx] == 1) : true);
  }
  const bool valid = (count > 0) && __all(allone);
  const float inv = valid ? 1.0f / (float)count : 0.0f;

  floatx4 sum[3] = {{0.f, 0.f, 0.f, 0.f}, {0.f, 0.f, 0.f, 0.f}, {0.f, 0.f, 0.f, 0.f}};
  const float* eb = emb + (size_t)b * Sn * Hn;
  int s = start;
  for (; s + 1 < end; s += 2) {
    const floatx4* r0 = (const floatx4*)(eb + (size_t)s * Hn);
    const floatx4* r1 = (const floatx4*)(eb + (size_t)(s + 1) * Hn);
#pragma unroll
    for (int j = 0; j < 3; ++j) sum[j] += r0[j * 64 + lane];
#pragma unroll
    for (int j = 0; j < 3; ++j) sum[j] += r1[j * 64 + lane];
  }
  if (s < end) {
    const floatx4* r0 = (const floatx4*)(eb + (size_t)s * Hn);
#pragma unroll
    for (int j = 0; j < 3; ++j) sum[j] += r0[j * 64 + lane];
  }

  const size_t rowbase = ((size_t)b * Wn + w) * Hn;
#pragma unroll
  for (int j = 0; j < 3; ++j) {
    short4v o;
#pragma unroll
    for (int c = 0; c < 4; ++c) {
      __hip_bfloat16 h = (__hip_bfloat16)(sum[j][c] * inv);
      o[c] = *reinterpret_cast<short*>(&h);
    }
    *(short4v*)&wa[rowbase + (size_t)(j * 64 + lane) * 4] = o;
  }
  if (lane == 0) out_masks[(size_t)b * Wn + w] = valid ? 1.0f : 0.0f;
}

// ------------- kernel 2: bf16 MFMA GEMM — 8-phase-density counted-vmcnt ---------
// A: (M=16384, K=768) bf16, Bt: (N=1024, K=768) bf16, C fp32.
// 256x256 tile, 512 thr = 8 waves (2M x 4N, 128x64 out/wave), BK=32,
// 24 K-tiles. 4-slot LDS ring (4 x 32 KiB = 128 KiB): iter kt computes slot
// kt%4 and stages tile kt+3 into slot (kt+3)%4, which is fully free by
// construction (consumed at iter kt-1). Per K-tile: 2 phases, each
// {<=8 ds_read_b128, 2 global_load_lds, barrier, lgkmcnt(0)+sched_barrier,
// setprio(1), 16 MFMA, setprio(0), barrier} — m201 phase density (T3).
// Counted s_waitcnt vmcnt(8) ONCE per K-tile (T4): outstanding <= tiles
// {kt+1,kt+2,kt+3} x4 loads = 12; keeping the 8 newest forces tile kt+1
// resident. Stage lead ~6 phases (~1500cy) > HBM latency. Tail: vmcnt(4) at
// kt=21, vmcnt(0) at kt=22. 2-bit XOR swizzle slot'=quad^(row&3), applied
// both-sides (pre-swizzled global source + swizzled ds_read): bank-uniform
// at BK=32 (all 8 16B-column groups get exactly 8 lanes). Final K-tile is
// peeled with the bias+store epilogue fused per m-half.
constexpr int GK = Hn;              // 768
constexpr int TSA = 256 * 32;       // shorts per A (or B) region = 16 KiB
constexpr int SLOT = 2 * TSA;       // A+B per ring slot = 32 KiB
constexpr int kGemmLds = 4 * SLOT * (int)sizeof(short);  // 131072 B
static_assert(kGemmLds == 131072, "LDS budget");

__global__ __launch_bounds__(512, 2) void k_gemm(const short* __restrict__ A,
                                                 const short* __restrict__ Bt,
                                                 const float* __restrict__ bias,
                                                 float* __restrict__ out) {
  extern __shared__ __align__(16) short ls[];  // 4 ring slots

  const int t = threadIdx.x;  // 0..511
  const int lane = t & 63, wave = t >> 6;
  const int wm = wave >> 2, wn = wave & 3;        // 2 x 4 wave grid
  const int lane16 = lane & 15, quad = lane >> 4;
  const int swz2 = lane16 & 3;

  const int mt = blockIdx.x & 63, nt = blockIdx.x >> 6;  // A-sharing blocks
  const int m0 = mt * 256, n0 = nt * 256;                // land on same XCD

  // staging: thread t covers rows rS(+128), physical 16B col-slot t&3;
  // pre-swizzled source col slot = (t&3) ^ (rS&3)   (involution)
  const int rS = t >> 2;                    // 0..127
  const int csw = ((t & 3) ^ (rS & 3)) * 8; // shorts
  const short* gAs = A + (size_t)(m0 + rS) * GK + csw;
  const short* gBs = Bt + (size_t)(n0 + rS) * GK + csw;
  const int dst0 = t * 8;                   // = rS*32 + (t&3)*8

  auto stage_a = [&](int slot, int kt) {  // 2 loads: A rows rS, rS+128
    short* d = ls + slot * SLOT + dst0;
    const short* g = gAs + kt * 32;
    load_lds16(g, d);
    load_lds16(g + (size_t)128 * GK, d + 4096);
  };
  auto stage_b = [&](int slot, int kt) {  // 2 loads: B rows rS, rS+128
    short* d = ls + slot * SLOT + TSA + dst0;
    const short* g = gBs + kt * 32;
    load_lds16(g, d);
    load_lds16(g + (size_t)128 * GK, d + 4096);
  };

  // fragment reads: row&3 == lane16&3 == swz2 for all fragment rows
  auto ld_a = [&](short8(&af)[4], int mh, const short* bufA) {
#pragma unroll
    for (int mf = 0; mf < 4; ++mf)
      af[mf] = *(const short8*)&bufA[(wm * 128 + mh * 64 + mf * 16 + lane16) * 32 +
                                     ((quad ^ swz2) << 3)];
  };
  auto ld_b = [&](short8(&bf)[4], const short* bufB) {
#pragma unroll
    for (int nf = 0; nf < 4; ++nf)
      bf[nf] = *(const short8*)&bufB[(wn * 64 + nf * 16 + lane16) * 32 +
                                     ((quad ^ swz2) << 3)];
  };

  floatx4 acc[8][4];
#pragma unroll
  for (int i = 0; i < 8; ++i)
#pragma unroll
    for (int j = 0; j < 4; ++j) acc[i][j] = (floatx4){0.f, 0.f, 0.f, 0.f};

  auto mm = [&](short8(&af)[4], short8(&bf)[4], int mh) {
    __builtin_amdgcn_s_setprio(1);
#pragma unroll
    for (int mf = 0; mf < 4; ++mf)
#pragma unroll
      for (int nf = 0; nf < 4; ++nf)
        acc[mh * 4 + mf][nf] = __builtin_amdgcn_mfma_f32_16x16x32_bf16(
            af[mf], bf[nf], acc[mh * 4 + mf][nf], 0, 0, 0);
    __builtin_amdgcn_s_setprio(0);
  };

  // prologue: stage tiles 0,1,2 into slots 0,1,2 (12 loads); keep 8 newest
  // outstanding -> tile 0 resident.
  stage_a(0, 0); stage_b(0, 0);
  stage_a(1, 1); stage_b(1, 1);
  stage_a(2, 2); stage_b(2, 2);
  asm volatile("s_waitcnt vmcnt(8)" ::: "memory");
  __builtin_amdgcn_sched_barrier(0);
  __builtin_amdgcn_s_barrier();

#pragma unroll 1
  for (int kt = 0; kt < 23; ++kt) {  // K-tiles 0..22 (kt=23 peeled below)
    const short* bufA = ls + (kt & 3) * SLOT;
    const short* bufB = bufA + TSA;
    const int ss = (kt + 3) & 3;
    const bool st = (kt <= 20);  // stage tile kt+3 (<= 23)
    short8 af[4], bf[4];

    // ---- phase 1: m-half 0 ----
    ld_a(af, 0, bufA);
    ld_b(bf, bufB);
    if (st) stage_a(ss, kt + 3);
    __builtin_amdgcn_s_barrier();
    asm volatile("s_waitcnt lgkmcnt(0)" ::: "memory");
    __builtin_amdgcn_sched_barrier(0);
    mm(af, bf, 0);
    __builtin_amdgcn_s_barrier();

    // ---- phase 2: m-half 1 (bf reused) ----
    ld_a(af, 1, bufA);
    if (st) stage_b(ss, kt + 3);
    __builtin_amdgcn_s_barrier();
    asm volatile("s_waitcnt lgkmcnt(0)" ::: "memory");
    __builtin_amdgcn_sched_barrier(0);
    mm(af, bf, 1);
    // iter boundary: counted wait -> tile kt+1 resident, newer stay in flight
    if (kt <= 20) {
      asm volatile("s_waitcnt vmcnt(8)" ::: "memory");
    } else if (kt == 21) {
      asm volatile("s_waitcnt vmcnt(4)" ::: "memory");
    } else {  // kt == 22
      asm volatile("s_waitcnt vmcnt(0)" ::: "memory");
    }
    __builtin_amdgcn_sched_barrier(0);
    __builtin_amdgcn_s_barrier();
  }

  // ---- peeled last K-tile (kt=23, slot 3): epilogue fused per m-half ----
  {
    const short* bufA = ls + 3 * SLOT;
    const short* bufB = bufA + TSA;
    short8 af[4], bf[4];

    float bv[4];
#pragma unroll
    for (int nf = 0; nf < 4; ++nf) bv[nf] = bias[n0 + wn * 64 + nf * 16 + lane16];

    // C/D layout: col = lane&15, row = quad*4 + r (m89/m91-verified)
    auto store_half = [&](int mh) {
#pragma unroll
      for (int mf = 0; mf < 4; ++mf) {
#pragma unroll
        for (int nf = 0; nf < 4; ++nf) {
          const int n = n0 + wn * 64 + nf * 16 + lane16;
#pragma unroll
          for (int r = 0; r < 4; ++r) {
            const int m = m0 + wm * 128 + (mh * 4 + mf) * 16 + quad * 4 + r;
            __builtin_nontemporal_store(acc[mh * 4 + mf][nf][r] + bv[nf],
                                        &out[(size_t)m * Dn + n]);
          }
        }
      }
    };

    ld_a(af, 0, bufA);
    ld_b(bf, bufB);
    asm volatile("s_waitcnt lgkmcnt(0)" ::: "memory");
    __builtin_amdgcn_sched_barrier(0);
    mm(af, bf, 0);
    store_half(0);  // overlaps remaining ds_read+MFMA

    ld_a(af, 1, bufA);
    asm volatile("s_waitcnt lgkmcnt(0)" ::: "memory");
    __builtin_amdgcn_sched_barrier(0);
    mm(af, bf, 1);
    store_half(1);
  }
}

extern "C" void kernel_launch(void* const* d_in, const int* in_sizes, int n_in,
                              void* d_out, int out_size, void* d_ws, size_t ws_size,
                              hipStream_t stream) {
  const float* emb    = (const float*)d_in[0];  // (8, 4096, 768)
  const float* proj_w = (const float*)d_in[1];  // (768, 1024)
  const float* proj_b = (const float*)d_in[2];  // (1024,)
  const int*   masks  = (const int*)d_in[3];    // (8, 4096)
  const int*   wid    = (const int*)d_in[4];    // (8, 4096)

  float* out = (float*)d_out;                       // (8, 2048, 1024) fp32
  float* out_masks = out + (size_t)Bn * Wn * Dn;    // (8, 2048) as 0.0/1.0

  __hip_bfloat16* wb = (__hip_bfloat16*)d_ws;            // B^T: (1024, 768) bf16
  __hip_bfloat16* wa = wb + (size_t)Dn * Hn;             // A:   (16384, 768) bf16

  // 1. transpose (first 768 blocks) ∥ segment means + masks (4096 blocks)
  k_front<<<dim3(768 + 4096), 256, 0, stream>>>(emb, proj_w, masks, wid, wb, wa,
                                                out_masks);

  // 2. projection GEMM + bias: 256x256 tiles, 256 blocks (1/CU), 4-slot ring,
  //    2-phase-per-BK32 fine interleave with counted vmcnt(8).
  (void)hipFuncSetAttribute((const void*)k_gemm,
                            hipFuncAttributeMaxDynamicSharedMemorySize, kGemmLds);
  k_gemm<<<dim3(256), 512, kGemmLds, stream>>>((const short*)wa, (const short*)wb,
                                               proj_b, out);
}